// Round 9
// baseline (383.071 us; speedup 1.0000x reference)
//
#include <hip/hip_runtime.h>

#define TT 128
#define DD 256
#define NH 8
#define HD 32
#define SCALEF 0.17677669529663687f
#define NEGV -1e9f

typedef short bf16x8 __attribute__((ext_vector_type(8)));
typedef float f32x4 __attribute__((ext_vector_type(4)));

__device__ inline unsigned short f2bf(float f) {
    unsigned u = __float_as_uint(f);
    unsigned r = (u + 0x7FFFu + ((u >> 16) & 1u)) >> 16;
    return (unsigned short)r;
}
__device__ inline unsigned pk2(float a, float b) {
    return (unsigned)f2bf(a) | ((unsigned)f2bf(b) << 16);
}

// ---------------------------------------------------------------------------
// Kernel 0: weights -> bf16 FRAGMENT-LINEAR layouts in ws.
// A 1KB "frag" = 64 lanes x 8 shorts; lane l holds (row l&15, k-offset (l>>4)*8+s).
//  conv W: frag id ((k*16 + jr)*8 + c32); row j = jr*16+(l&15); ci = c32*32+(l>>4)*8+s
//  v/out W: frag id (er*8 + c32); row e = er*16+(l&15); d/ci = c32*32+(l>>4)*8+s
// Block 1280 detects kpm storage width (uint8 vs int32).
// ---------------------------------------------------------------------------
__global__ void cvt_weights_kernel(
    const float* __restrict__ wq, const float* __restrict__ wk,
    const float* __restrict__ vw, const float* __restrict__ ow,
    const unsigned char* __restrict__ kpm8,
    unsigned short* __restrict__ wqf, unsigned short* __restrict__ wkf,
    unsigned short* __restrict__ vwf, unsigned short* __restrict__ owf,
    int* __restrict__ flagp)
{
    if (blockIdx.x == 1280) {
        __shared__ int f;
        if (threadIdx.x == 0) f = 0;
        __syncthreads();
        bool loc = false;
        for (int i = threadIdx.x; i < 4096; i += 256)
            if ((i & 3) && kpm8[i]) loc = true;
        if (loc) f = 1;
        __syncthreads();
        if (threadIdx.x == 0) *flagp = f;
        return;
    }
    int t = blockIdx.x * 256 + threadIdx.x;          // 0..327679
    if (t < 196608) {
        int f = t >> 9, r = t & 511, l = r >> 3, s = r & 7;
        int k = f >> 7, jr = (f >> 3) & 15, c32 = f & 7;
        int j = jr * 16 + (l & 15);
        int ci = c32 * 32 + (l >> 4) * 8 + s;
        int src = j * 768 + ci * 3 + k;
        wqf[t] = f2bf(wq[src]);
        wkf[t] = f2bf(wk[src]);
    } else {
        int o = t - 196608;
        int oo = o & 65535;
        int f = oo >> 9, r = oo & 511, l = r >> 3, s = r & 7;
        int er = f >> 3, c32 = f & 7;
        int e = er * 16 + (l & 15);
        int d = c32 * 32 + (l >> 4) * 8 + s;
        if (o < 65536) vwf[oo] = f2bf(vw[e * 256 + d]);
        else           owf[oo] = f2bf(ow[e * 256 + d]);
    }
}

// ---------------------------------------------------------------------------
// Kernel 1: projections. grid (512 bn, 3 which), 512 threads / 8 waves.
// Single-phase X staging (whole tile in LDS, pitch 264). MFMA loop with:
//  - depth-2 double-buffered W-frag register prefetch (iter i+2 issued during
//    iter i's MFMAs; prologue hoisted ABOVE staging so HBM latency covers it)
//  - per-wave c32 rotation ((c32+wv)&7) to desynchronize the lockstep waves'
//    L2 requests (accumulation order change is fp-commutative, bf16-tolerant)
// (512,4): VGPR cap 128, no spill (R6 lesson); LDS 68.6KB -> 2 blocks/CU.
// ---------------------------------------------------------------------------
#define XP 264   // LDS row pitch in shorts

__global__ __launch_bounds__(512, 4) void proj_kernel(
    const float* __restrict__ query, const float* __restrict__ key,
    const float* __restrict__ value,
    const unsigned short* __restrict__ wqf, const unsigned short* __restrict__ wkf,
    const unsigned short* __restrict__ vwf,
    const float* __restrict__ bq, const float* __restrict__ bk,
    const float* __restrict__ vbias,
    short* __restrict__ qkb, short* __restrict__ vbuf)
{
    __shared__ __align__(16) short Xs[130 * XP];   // 68.6 KB

    const int tid = threadIdx.x;
    const int bn = blockIdx.x, which = blockIdx.y;
    const int lane = tid & 63, wv = tid >> 6;
    const int lr = lane & 15, rg = lane >> 4, k8 = rg * 8;

    const float* __restrict__ X =
        (which == 0 ? query : which == 1 ? key : value) + (size_t)bn * TT * DD;

    if (which < 2) {
        const unsigned short* __restrict__ W = which ? wkf : wqf;
        const float* __restrict__ bias = which ? bk : bq;
        const int j0 = (wv & 3) * 64;     // output-channel tile
        const int t0 = (wv >> 2) * 64;    // time tile
        const int jr0 = j0 >> 4;

        // ---- W prologue (iters 0,1) issued BEFORE staging: HBM covers L2 ----
        bf16x8 abuf[2][4];
        #pragma unroll
        for (int p = 0; p < 2; ++p) {
            const int k = 0, c32 = (p + wv) & 7;
            #pragma unroll
            for (int mf = 0; mf < 4; ++mf)
                abuf[p][mf] = *(const bf16x8*)(W +
                    ((((k * 16 + jr0 + mf) * 8 + c32) << 9) + lane * 8));
        }

        // ---- stage the WHOLE X tile: rows t=-1..128 (halo), 256 ch ----
        for (int i = tid; i < 130 * 64; i += 512) {
            int row = i >> 6, c4 = i & 63, g = row - 1;
            float4 x4 = make_float4(0.f, 0.f, 0.f, 0.f);
            if (g >= 0 && g < TT)
                x4 = *(const float4*)(X + g * DD + c4 * 4);
            uint2 p; p.x = pk2(x4.x, x4.y); p.y = pk2(x4.z, x4.w);
            *(uint2*)&Xs[row * XP + c4 * 4] = p;
        }
        __syncthreads();

        f32x4 acc[4][4];
        #pragma unroll
        for (int mf = 0; mf < 4; ++mf)
            #pragma unroll
            for (int r = 0; r < 4; ++r) {
                float bv = bias[j0 + mf * 16 + rg * 4 + r];
                #pragma unroll
                for (int nf = 0; nf < 4; ++nf) acc[mf][nf][r] = bv;
            }

        // ---- 24 iterations, no barriers, depth-2 W prefetch ----
        #pragma unroll
        for (int it = 0; it < 24; ++it) {
            const int cur = it & 1;
            const int k = it >> 3, c32 = ((it & 7) + wv) & 7;
            bf16x8 bb[4];
            #pragma unroll
            for (int nf = 0; nf < 4; ++nf)
                bb[nf] = *(const bf16x8*)&Xs[(t0 + nf * 16 + lr + k) * XP
                                             + c32 * 32 + k8];
            bf16x8 aa[4];
            #pragma unroll
            for (int mf = 0; mf < 4; ++mf) aa[mf] = abuf[cur][mf];
            if (it + 2 < 24) {
                const int k2 = (it + 2) >> 3, c2 = (((it + 2) & 7) + wv) & 7;
                #pragma unroll
                for (int mf = 0; mf < 4; ++mf)
                    abuf[cur][mf] = *(const bf16x8*)(W +
                        ((((k2 * 16 + jr0 + mf) * 8 + c2) << 9) + lane * 8));
            }
            #pragma unroll
            for (int mf = 0; mf < 4; ++mf)
                #pragma unroll
                for (int nf = 0; nf < 4; ++nf)
                    acc[mf][nf] = __builtin_amdgcn_mfma_f32_16x16x32_bf16(
                        aa[mf], bb[nf], acc[mf][nf], 0, 0, 0);
        }
        // frag-linear store: frag (tr*8 + jc), coalesced 512B per (mf,nf)
        short* cell = qkb + (size_t)bn * 65536 + which * 32768;
        #pragma unroll
        for (int mf = 0; mf < 4; ++mf)
            #pragma unroll
            for (int nf = 0; nf < 4; ++nf) {
                int fr = ((t0 >> 4) + nf) * 8 + (j0 >> 5) + (mf >> 1);
                int off = (fr << 9) + (lr + 16 * ((mf & 1) * 2 + (rg >> 1))) * 8
                          + (rg & 1) * 4;
                uint2 p;
                p.x = pk2(acc[mf][nf][0], acc[mf][nf][1]);
                p.y = pk2(acc[mf][nf][2], acc[mf][nf][3]);
                *(uint2*)&cell[off] = p;
            }
    } else {
        const int e0 = (wv & 3) * 64;
        const int t0 = (wv >> 2) * 64;
        const int er0 = e0 >> 4;

        // ---- vwf prologue (iters 0,1) before staging ----
        bf16x8 vbuf2[2][4];
        #pragma unroll
        for (int p = 0; p < 2; ++p) {
            const int c32 = (p + wv) & 7;
            #pragma unroll
            for (int nf = 0; nf < 4; ++nf)
                vbuf2[p][nf] = *(const bf16x8*)(vwf +
                    ((((er0 + nf) * 8 + c32) << 9) + lane * 8));
        }

        // ---- stage whole V input tile: 128 rows x 256 ch ----
        for (int i = tid; i < 128 * 64; i += 512) {
            int row = i >> 6, c4 = i & 63;
            float4 x4 = *(const float4*)(X + row * DD + c4 * 4);
            uint2 p; p.x = pk2(x4.x, x4.y); p.y = pk2(x4.z, x4.w);
            *(uint2*)&Xs[row * XP + c4 * 4] = p;
        }
        __syncthreads();

        f32x4 acc4[4][4];
        #pragma unroll
        for (int nf = 0; nf < 4; ++nf) {
            float bv = vbias[e0 + nf * 16 + lr];
            #pragma unroll
            for (int mf = 0; mf < 4; ++mf)
                #pragma unroll
                for (int r = 0; r < 4; ++r) acc4[mf][nf][r] = bv;
        }

        #pragma unroll
        for (int it = 0; it < 8; ++it) {
            const int cur = it & 1;
            const int c32 = (it + wv) & 7;
            bf16x8 aa[4];
            #pragma unroll
            for (int mf = 0; mf < 4; ++mf)
                aa[mf] = *(const bf16x8*)&Xs[(t0 + mf * 16 + lr) * XP
                                             + c32 * 32 + k8];
            bf16x8 bb[4];
            #pragma unroll
            for (int nf = 0; nf < 4; ++nf) bb[nf] = vbuf2[cur][nf];
            if (it + 2 < 8) {
                const int c2 = ((it + 2) + wv) & 7;
                #pragma unroll
                for (int nf = 0; nf < 4; ++nf)
                    vbuf2[cur][nf] = *(const bf16x8*)(vwf +
                        ((((er0 + nf) * 8 + c2) << 9) + lane * 8));
            }
            #pragma unroll
            for (int mf = 0; mf < 4; ++mf)
                #pragma unroll
                for (int nf = 0; nf < 4; ++nf)
                    acc4[mf][nf] = __builtin_amdgcn_mfma_f32_16x16x32_bf16(
                        aa[mf], bb[nf], acc4[mf][nf], 0, 0, 0);
        }
        // V^T frag-linear store: frag (er*4 + kc), kc = tk-chunk
        short* vcell = vbuf + (size_t)bn * 32768;
        #pragma unroll
        for (int mf = 0; mf < 4; ++mf)
            #pragma unroll
            for (int nf = 0; nf < 4; ++nf) {
                int fr = (((e0 >> 4) + nf) << 2) + (t0 >> 5) + (mf >> 1);
                int off = (fr << 9) + (lr + 16 * ((mf & 1) * 2 + (rg >> 1))) * 8
                          + (rg & 1) * 4;
                uint2 p;
                p.x = pk2(acc4[mf][nf][0], acc4[mf][nf][1]);
                p.y = pk2(acc4[mf][nf][2], acc4[mf][nf][3]);
                *(uint2*)&vcell[off] = p;
            }
    }
}

// ---------------------------------------------------------------------------
// Kernel 2: attention. grid 4096 = (bn,h) XCD-swizzled, 4 waves.
// All operands frag-linear coalesced loads. x transposed via LDS and stored
// frag-linear IN PLACE over this block's own K-cell frags (jc=h), which only
// this block reads (barrier-protected). (256,3): 3 blocks/CU, VGPR 124<=170.
// ---------------------------------------------------------------------------
__global__ __launch_bounds__(256, 3) void attn_kernel(
    short* __restrict__ qkb, const short* __restrict__ vbuf,
    const unsigned char* __restrict__ kpm8, const int* __restrict__ kpm32,
    const int* __restrict__ amask, const int* __restrict__ flagp)
{
    __shared__ __align__(16) short Ps[4 * 32 * 136];   // 34.8 KB, per-wave P
    __shared__ __align__(16) short xl[128 * 40];       // 10 KB
    __shared__ unsigned char maskb[2048];

    const int tid = threadIdx.x;
    int bid = blockIdx.x;
    int bnh = (bid & 7) * 512 + (bid >> 3);
    const int bn = bnh >> 3, h = bnh & 7;

    const int lane = tid & 63, wv = tid >> 6;
    const int lr = lane & 15, rg = lane >> 4, k8 = rg * 8;
    const int m0 = wv * 32;
    const bool kpm_u8 = (*flagp != 0);

    // combined mask bitmask
    {
        const unsigned char* kp8 = kpm8 + (size_t)bn * TT;
        const int* kp32 = kpm32 + (size_t)bn * TT;
        for (int i = tid; i < 2048; i += 256) {
            int row = i >> 4, c = i & 15;
            unsigned m = 0;
            #pragma unroll
            for (int nf = 0; nf < 8; ++nf) {
                int col = c + nf * 16;
                int kdead = kpm_u8 ? (int)kp8[col] : kp32[col];
                int adead = (amask[row * TT + col] == 0) ? 1 : 0;
                m |= (unsigned)(((kdead != 0) ? 1 : 0) | adead) << nf;
            }
            maskb[i] = (unsigned char)m;
        }
    }

    const short* qcell = qkb + (size_t)bn * 65536;
    short* kcell = qkb + (size_t)bn * 65536 + 32768;

    // frag-linear coalesced loads
    bf16x8 qa[2];
    #pragma unroll
    for (int mf = 0; mf < 2; ++mf)
        qa[mf] = *(const bf16x8*)(qcell + ((((wv * 2 + mf) * 8 + h) << 9)
                                           + lane * 8));
    bf16x8 kb[8];
    #pragma unroll
    for (int nf = 0; nf < 8; ++nf)
        kb[nf] = *(const bf16x8*)(kcell + (((nf * 8 + h) << 9) + lane * 8));

    __syncthreads();   // maskb ready

    // QK^T
    f32x4 sc[2][8];
    #pragma unroll
    for (int nf = 0; nf < 8; ++nf) {
        f32x4 z = { 0.f, 0.f, 0.f, 0.f };
        sc[0][nf] = __builtin_amdgcn_mfma_f32_16x16x32_bf16(qa[0], kb[nf], z, 0, 0, 0);
        sc[1][nf] = __builtin_amdgcn_mfma_f32_16x16x32_bf16(qa[1], kb[nf], z, 0, 0, 0);
    }

    // mask + softmax (16-lane groups own a row)
    float linv[2][4];
    #pragma unroll
    for (int mf = 0; mf < 2; ++mf)
        #pragma unroll
        for (int r = 0; r < 4; ++r) {
            int row = m0 + mf * 16 + rg * 4 + r;
            unsigned mb = maskb[row * 16 + lr];
            float v[8];
            float vmax = -3.4e38f;
            #pragma unroll
            for (int nf = 0; nf < 8; ++nf) {
                float t = sc[mf][nf][r] * SCALEF;
                if ((mb >> nf) & 1) t = NEGV;
                v[nf] = t;
                vmax = fmaxf(vmax, t);
            }
            #pragma unroll
            for (int d = 1; d < 16; d <<= 1)
                vmax = fmaxf(vmax, __shfl_xor(vmax, d, 64));
            float ls = 0.f;
            #pragma unroll
            for (int nf = 0; nf < 8; ++nf) {
                float p = __expf(v[nf] - vmax);
                ls += p;
                sc[mf][nf][r] = p;
            }
            #pragma unroll
            for (int d = 1; d < 16; d <<= 1)
                ls += __shfl_xor(ls, d, 64);
            linv[mf][r] = 1.f / ls;
        }

    // P -> per-wave LDS
    short* Pw = Ps + wv * 32 * 136;
    #pragma unroll
    for (int mf = 0; mf < 2; ++mf)
        #pragma unroll
        for (int r = 0; r < 4; ++r) {
            int q = mf * 16 + rg * 4 + r;
            #pragma unroll
            for (int nf = 0; nf < 8; ++nf)
                Pw[q * 136 + nf * 16 + lr] = (short)f2bf(sc[mf][nf][r]);
        }

    // PV: A = P (LDS), B = V^T frags (global, coalesced)
    f32x4 xacc[2][2];
    {
        f32x4 z = { 0.f, 0.f, 0.f, 0.f };
        xacc[0][0] = z; xacc[0][1] = z; xacc[1][0] = z; xacc[1][1] = z;
    }
    const short* vcell = vbuf + (size_t)bn * 32768;
    #pragma unroll
    for (int kk = 0; kk < 4; ++kk) {
        bf16x8 pa0 = *(const bf16x8*)&Pw[(lr) * 136 + kk * 32 + k8];
        bf16x8 pa1 = *(const bf16x8*)&Pw[(16 + lr) * 136 + kk * 32 + k8];
        bf16x8 vb0 = *(const bf16x8*)(vcell + ((((h * 2 + 0) * 4 + kk) << 9) + lane * 8));
        bf16x8 vb1 = *(const bf16x8*)(vcell + ((((h * 2 + 1) * 4 + kk) << 9) + lane * 8));
        xacc[0][0] = __builtin_amdgcn_mfma_f32_16x16x32_bf16(pa0, vb0, xacc[0][0], 0, 0, 0);
        xacc[0][1] = __builtin_amdgcn_mfma_f32_16x16x32_bf16(pa0, vb1, xacc[0][1], 0, 0, 0);
        xacc[1][0] = __builtin_amdgcn_mfma_f32_16x16x32_bf16(pa1, vb0, xacc[1][0], 0, 0, 0);
        xacc[1][1] = __builtin_amdgcn_mfma_f32_16x16x32_bf16(pa1, vb1, xacc[1][1], 0, 0, 0);
    }

    __syncthreads();   // all waves' K-frag loads landed before x overwrites K

    // x -> LDS (normalized bf16)
    #pragma unroll
    for (int mf = 0; mf < 2; ++mf)
        #pragma unroll
        for (int nf = 0; nf < 2; ++nf)
            #pragma unroll
            for (int r = 0; r < 4; ++r) {
                int t = m0 + mf * 16 + rg * 4 + r;
                xl[t * 40 + nf * 16 + lr] =
                    (short)f2bf(xacc[mf][nf][r] * linv[mf][r]);
            }
    __syncthreads();

    // coalesced frag-linear x store over K-cell frags (tr*8 + h)
    #pragma unroll
    for (int p = 0; p < 2; ++p) {
        int idx = tid + p * 256;          // 0..511
        int f = idx >> 6, l = idx & 63;
        int row = f * 16 + (l & 15), c8 = (l >> 4) * 8;
        uint4 v = *(const uint4*)&xl[row * 40 + c8];
        *(uint4*)(kcell + (((f * 8 + h) << 9) + l * 8)) = v;
    }
}

// ---------------------------------------------------------------------------
// Kernel 3: out-projection. No LDS, no barriers: A (x) and B (out-W) frags
// read coalesced from global; fp32 epilogue into d_out cell. (256,2).
// ---------------------------------------------------------------------------
__global__ __launch_bounds__(256, 2) void out_proj_mfma(
    short* __restrict__ qkb, const unsigned short* __restrict__ owf,
    const float* __restrict__ ob)
{
    const int tid = threadIdx.x;
    const int lane = tid & 63, wv = tid >> 6;
    const int lr = lane & 15, rg = lane >> 4;
    const int m0 = wv * 32;
    const short* xf = qkb + (size_t)blockIdx.x * 65536 + 32768;
    float* fcell = (float*)qkb + (size_t)blockIdx.x * 32768;

    f32x4 acc[2][16];
    {
        f32x4 z = { 0.f, 0.f, 0.f, 0.f };
        #pragma unroll
        for (int nf = 0; nf < 16; ++nf) { acc[0][nf] = z; acc[1][nf] = z; }
    }

    #pragma unroll
    for (int dc = 0; dc < 8; ++dc) {
        bf16x8 a0 = *(const bf16x8*)(xf + ((((wv * 2 + 0) * 8 + dc) << 9) + lane * 8));
        bf16x8 a1 = *(const bf16x8*)(xf + ((((wv * 2 + 1) * 8 + dc) << 9) + lane * 8));
        #pragma unroll
        for (int nf = 0; nf < 16; ++nf) {
            bf16x8 b = *(const bf16x8*)(owf + (((nf * 8 + dc) << 9) + lane * 8));
            acc[0][nf] = __builtin_amdgcn_mfma_f32_16x16x32_bf16(a0, b, acc[0][nf], 0, 0, 0);
            acc[1][nf] = __builtin_amdgcn_mfma_f32_16x16x32_bf16(a1, b, acc[1][nf], 0, 0, 0);
        }
    }

    #pragma unroll
    for (int mf = 0; mf < 2; ++mf)
        #pragma unroll
        for (int nf = 0; nf < 16; ++nf) {
            float bb = ob[nf * 16 + lr];
            #pragma unroll
            for (int r = 0; r < 4; ++r)
                fcell[(m0 + mf * 16 + rg * 4 + r) * DD + nf * 16 + lr] =
                    acc[mf][nf][r] + bb;
        }
}

extern "C" void kernel_launch(void* const* d_in, const int* in_sizes, int n_in,
                              void* d_out, int out_size, void* d_ws, size_t ws_size,
                              hipStream_t stream) {
    (void)in_sizes; (void)n_in; (void)out_size; (void)ws_size;
    const float* query = (const float*)d_in[0];
    const float* key   = (const float*)d_in[1];
    const float* value = (const float*)d_in[2];
    const void*  kpm   = d_in[3];
    const int*   amask = (const int*)d_in[4];
    const float* wq = (const float*)d_in[5];
    const float* bq = (const float*)d_in[6];
    const float* wk = (const float*)d_in[7];
    const float* bk = (const float*)d_in[8];
    const float* vw = (const float*)d_in[9];
    const float* vb = (const float*)d_in[10];
    const float* ow = (const float*)d_in[11];
    const float* ob = (const float*)d_in[12];

    short* qkb = (short*)d_out;
    unsigned short* wqf = (unsigned short*)d_ws;        // 196608
    unsigned short* wkf = wqf + 196608;                 // 196608
    unsigned short* vwf = wkf + 196608;                 // 65536
    unsigned short* owf = vwf + 65536;                  // 65536  (end 524288)
    int* flagp = (int*)((short*)d_ws + 524288);
    short* vbuf = (short*)d_ws + 524296;                // 16.77M shorts (32 MiB)

    cvt_weights_kernel<<<dim3(1281), dim3(256), 0, stream>>>(
        wq, wk, vw, ow, (const unsigned char*)kpm, wqf, wkf, vwf, owf, flagp);

    proj_kernel<<<dim3(512, 3), dim3(512), 0, stream>>>(
        query, key, value, wqf, wkf, vwf, bq, bk, vb, qkb, vbuf);

    attn_kernel<<<dim3(4096), dim3(256), 0, stream>>>(
        qkb, vbuf, (const unsigned char*)kpm, (const int*)kpm, amask, flagp);

    out_proj_mfma<<<dim3(512), dim3(256), 0, stream>>>(qkb, owf, ob);
}

// Round 10
// 169.701 us; speedup vs baseline: 2.2573x; 2.2573x over previous
//
#include <hip/hip_runtime.h>

#define TT 128
#define DD 256
#define NH 8
#define HD 32
#define SCALEF 0.17677669529663687f
#define NEGV -1e9f

typedef short bf16x8 __attribute__((ext_vector_type(8)));
typedef float f32x4 __attribute__((ext_vector_type(4)));

__device__ inline unsigned short f2bf(float f) {
    unsigned u = __float_as_uint(f);
    unsigned r = (u + 0x7FFFu + ((u >> 16) & 1u)) >> 16;
    return (unsigned short)r;
}
__device__ inline unsigned pk2(float a, float b) {
    return (unsigned)f2bf(a) | ((unsigned)f2bf(b) << 16);
}

// ---------------------------------------------------------------------------
// Kernel 0: weights -> bf16 FRAGMENT-LINEAR layouts in ws.
// A 1KB "frag" = 64 lanes x 8 shorts; lane l holds (row l&15, k-offset (l>>4)*8+s).
//  conv W: frag id ((k*16 + jr)*8 + c32); row j = jr*16+(l&15); ci = c32*32+(l>>4)*8+s
//  v/out W: frag id (er*8 + c32); row e = er*16+(l&15); d/ci = c32*32+(l>>4)*8+s
// Block 1280 detects kpm storage width (uint8 vs int32).
// ---------------------------------------------------------------------------
__global__ void cvt_weights_kernel(
    const float* __restrict__ wq, const float* __restrict__ wk,
    const float* __restrict__ vw, const float* __restrict__ ow,
    const unsigned char* __restrict__ kpm8,
    unsigned short* __restrict__ wqf, unsigned short* __restrict__ wkf,
    unsigned short* __restrict__ vwf, unsigned short* __restrict__ owf,
    int* __restrict__ flagp)
{
    if (blockIdx.x == 1280) {
        __shared__ int f;
        if (threadIdx.x == 0) f = 0;
        __syncthreads();
        bool loc = false;
        for (int i = threadIdx.x; i < 4096; i += 256)
            if ((i & 3) && kpm8[i]) loc = true;
        if (loc) f = 1;
        __syncthreads();
        if (threadIdx.x == 0) *flagp = f;
        return;
    }
    int t = blockIdx.x * 256 + threadIdx.x;          // 0..327679
    if (t < 196608) {
        int f = t >> 9, r = t & 511, l = r >> 3, s = r & 7;
        int k = f >> 7, jr = (f >> 3) & 15, c32 = f & 7;
        int j = jr * 16 + (l & 15);
        int ci = c32 * 32 + (l >> 4) * 8 + s;
        int src = j * 768 + ci * 3 + k;
        wqf[t] = f2bf(wq[src]);
        wkf[t] = f2bf(wk[src]);
    } else {
        int o = t - 196608;
        int oo = o & 65535;
        int f = oo >> 9, r = oo & 511, l = r >> 3, s = r & 7;
        int er = f >> 3, c32 = f & 7;
        int e = er * 16 + (l & 15);
        int d = c32 * 32 + (l >> 4) * 8 + s;
        if (o < 65536) vwf[oo] = f2bf(vw[e * 256 + d]);
        else           owf[oo] = f2bf(ow[e * 256 + d]);
    }
}

// ---------------------------------------------------------------------------
// Kernel 1: projections — EXACT R8 form (127us, no spills). grid (512,3),
// 512 thr / 8 waves. Single-phase whole-tile X staging, one barrier, 24/8
// uninterrupted MFMA iterations; frag-linear outputs. (512,4): cap 128.
// ---------------------------------------------------------------------------
#define XP 264   // LDS row pitch in shorts

__global__ __launch_bounds__(512, 4) void proj_kernel(
    const float* __restrict__ query, const float* __restrict__ key,
    const float* __restrict__ value,
    const unsigned short* __restrict__ wqf, const unsigned short* __restrict__ wkf,
    const unsigned short* __restrict__ vwf,
    const float* __restrict__ bq, const float* __restrict__ bk,
    const float* __restrict__ vbias,
    short* __restrict__ qkb, short* __restrict__ vbuf)
{
    __shared__ __align__(16) short Xs[130 * XP];   // 68.6 KB

    const int tid = threadIdx.x;
    const int bn = blockIdx.x, which = blockIdx.y;
    const int lane = tid & 63, wv = tid >> 6;
    const int lr = lane & 15, rg = lane >> 4, k8 = rg * 8;

    const float* __restrict__ X =
        (which == 0 ? query : which == 1 ? key : value) + (size_t)bn * TT * DD;

    if (which < 2) {
        const unsigned short* __restrict__ W = which ? wkf : wqf;
        const float* __restrict__ bias = which ? bk : bq;
        const int j0 = (wv & 3) * 64;     // output-channel tile
        const int t0 = (wv >> 2) * 64;    // time tile

        // ---- stage the WHOLE X tile: rows t=-1..128 (halo), 256 ch ----
        for (int i = tid; i < 130 * 64; i += 512) {
            int row = i >> 6, c4 = i & 63, g = row - 1;
            float4 x4 = make_float4(0.f, 0.f, 0.f, 0.f);
            if (g >= 0 && g < TT)
                x4 = *(const float4*)(X + g * DD + c4 * 4);
            uint2 p; p.x = pk2(x4.x, x4.y); p.y = pk2(x4.z, x4.w);
            *(uint2*)&Xs[row * XP + c4 * 4] = p;
        }
        __syncthreads();

        f32x4 acc[4][4];
        #pragma unroll
        for (int mf = 0; mf < 4; ++mf)
            #pragma unroll
            for (int r = 0; r < 4; ++r) {
                float bv = bias[j0 + mf * 16 + rg * 4 + r];
                #pragma unroll
                for (int nf = 0; nf < 4; ++nf) acc[mf][nf][r] = bv;
            }

        // ---- all 24 k-groups, no barriers ----
        #pragma unroll
        for (int k = 0; k < 3; ++k) {
            #pragma unroll
            for (int c32 = 0; c32 < 8; ++c32) {
                bf16x8 aa[4];
                #pragma unroll
                for (int mf = 0; mf < 4; ++mf)
                    aa[mf] = *(const bf16x8*)(W +
                        ((((k * 16 + (j0 >> 4) + mf) * 8 + c32) << 9)
                         + lane * 8));
                bf16x8 bb[4];
                #pragma unroll
                for (int nf = 0; nf < 4; ++nf)
                    bb[nf] = *(const bf16x8*)&Xs[(t0 + nf * 16 + lr + k) * XP
                                                 + c32 * 32 + k8];
                #pragma unroll
                for (int mf = 0; mf < 4; ++mf)
                    #pragma unroll
                    for (int nf = 0; nf < 4; ++nf)
                        acc[mf][nf] = __builtin_amdgcn_mfma_f32_16x16x32_bf16(
                            aa[mf], bb[nf], acc[mf][nf], 0, 0, 0);
            }
        }
        // frag-linear store: frag (tr*8 + jc), coalesced 512B per (mf,nf)
        short* cell = qkb + (size_t)bn * 65536 + which * 32768;
        #pragma unroll
        for (int mf = 0; mf < 4; ++mf)
            #pragma unroll
            for (int nf = 0; nf < 4; ++nf) {
                int fr = ((t0 >> 4) + nf) * 8 + (j0 >> 5) + (mf >> 1);
                int off = (fr << 9) + (lr + 16 * ((mf & 1) * 2 + (rg >> 1))) * 8
                          + (rg & 1) * 4;
                uint2 p;
                p.x = pk2(acc[mf][nf][0], acc[mf][nf][1]);
                p.y = pk2(acc[mf][nf][2], acc[mf][nf][3]);
                *(uint2*)&cell[off] = p;
            }
    } else {
        const int e0 = (wv & 3) * 64;
        const int t0 = (wv >> 2) * 64;

        // ---- stage whole V input tile: 128 rows x 256 ch ----
        for (int i = tid; i < 128 * 64; i += 512) {
            int row = i >> 6, c4 = i & 63;
            float4 x4 = *(const float4*)(X + row * DD + c4 * 4);
            uint2 p; p.x = pk2(x4.x, x4.y); p.y = pk2(x4.z, x4.w);
            *(uint2*)&Xs[row * XP + c4 * 4] = p;
        }
        __syncthreads();

        f32x4 acc4[4][4];
        #pragma unroll
        for (int nf = 0; nf < 4; ++nf) {
            float bv = vbias[e0 + nf * 16 + lr];
            #pragma unroll
            for (int mf = 0; mf < 4; ++mf)
                #pragma unroll
                for (int r = 0; r < 4; ++r) acc4[mf][nf][r] = bv;
        }

        #pragma unroll
        for (int c32 = 0; c32 < 8; ++c32) {
            bf16x8 aa[4];
            #pragma unroll
            for (int mf = 0; mf < 4; ++mf)
                aa[mf] = *(const bf16x8*)&Xs[(t0 + mf * 16 + lr) * XP
                                             + c32 * 32 + k8];
            bf16x8 bb[4];
            #pragma unroll
            for (int nf = 0; nf < 4; ++nf)
                bb[nf] = *(const bf16x8*)(vwf +
                    (((((e0 >> 4) + nf) * 8 + c32) << 9) + lane * 8));
            #pragma unroll
            for (int mf = 0; mf < 4; ++mf)
                #pragma unroll
                for (int nf = 0; nf < 4; ++nf)
                    acc4[mf][nf] = __builtin_amdgcn_mfma_f32_16x16x32_bf16(
                        aa[mf], bb[nf], acc4[mf][nf], 0, 0, 0);
        }
        // V^T frag-linear store: frag (er*4 + kc), kc = tk-chunk
        short* vcell = vbuf + (size_t)bn * 32768;
        #pragma unroll
        for (int mf = 0; mf < 4; ++mf)
            #pragma unroll
            for (int nf = 0; nf < 4; ++nf) {
                int fr = (((e0 >> 4) + nf) << 2) + (t0 >> 5) + (mf >> 1);
                int off = (fr << 9) + (lr + 16 * ((mf & 1) * 2 + (rg >> 1))) * 8
                          + (rg & 1) * 4;
                uint2 p;
                p.x = pk2(acc4[mf][nf][0], acc4[mf][nf][1]);
                p.y = pk2(acc4[mf][nf][2], acc4[mf][nf][3]);
                *(uint2*)&vcell[off] = p;
            }
    }
}

// ---------------------------------------------------------------------------
// Kernel 2: FUSED attention + out-projection. grid 512 (bn, XCD-swizzled),
// 512 threads / 8 waves; wave = head. Per wave: 4 m-tile-pairs of
// {QK^T, masked softmax, P->wave-private LDS, PV} writing bf16 x into the
// shared xs[128][264] tile; one barrier; then out-proj (wave owns 16 rows,
// A from xs LDS, B = owf frags from L2 shared by all waves via L1), fp32
// epilogue over the bn cell (q/k reads all complete pre-barrier).
// LDS 136KB -> 1 block/CU; (512,2) -> VGPR cap 256 (no spill).
// ---------------------------------------------------------------------------
__global__ __launch_bounds__(512, 2) void attn_out_fused(
    short* qkb, const short* __restrict__ vbuf,
    const unsigned short* __restrict__ owf, const float* __restrict__ ob,
    const unsigned char* __restrict__ kpm8, const int* __restrict__ kpm32,
    const int* __restrict__ amask, const int* __restrict__ flagp)
{
    __shared__ __align__(16) short Ps[8 * 32 * 136];   // 69.6 KB, per-wave P
    __shared__ __align__(16) short xs[128 * XP];       // 67.6 KB, x (bf16)
    __shared__ unsigned char maskb[2048];

    const int tid = threadIdx.x;
    const int bid = blockIdx.x;
    const int bn = (bid & 7) * 64 + (bid >> 3);        // XCD swizzle
    const int lane = tid & 63, wv = tid >> 6;          // wv = head
    const int lr = lane & 15, rg = lane >> 4, k8 = rg * 8;
    const bool kpm_u8 = (*flagp != 0);

    // combined mask bitmask (all 512 threads)
    {
        const unsigned char* kp8 = kpm8 + (size_t)bn * TT;
        const int* kp32 = kpm32 + (size_t)bn * TT;
        for (int i = tid; i < 2048; i += 512) {
            int row = i >> 4, c = i & 15;
            unsigned m = 0;
            #pragma unroll
            for (int nf = 0; nf < 8; ++nf) {
                int col = c + nf * 16;
                int kdead = kpm_u8 ? (int)kp8[col] : kp32[col];
                int adead = (amask[row * TT + col] == 0) ? 1 : 0;
                m |= (unsigned)(((kdead != 0) ? 1 : 0) | adead) << nf;
            }
            maskb[i] = (unsigned char)m;
        }
    }

    const short* qcell = qkb + (size_t)bn * 65536;
    const short* kcell = qcell + 32768;
    const short* vcell = vbuf + (size_t)bn * 32768;

    // K frags for this head (held across all m-tiles)
    bf16x8 kb[8];
    #pragma unroll
    for (int nf = 0; nf < 8; ++nf)
        kb[nf] = *(const bf16x8*)(kcell + (((nf * 8 + wv) << 9) + lane * 8));

    __syncthreads();   // maskb ready

    short* Pw = Ps + wv * 32 * 136;

    #pragma unroll
    for (int mtp = 0; mtp < 4; ++mtp) {
        // Q frags for this m-tile pair
        bf16x8 qa[2];
        #pragma unroll
        for (int mf = 0; mf < 2; ++mf)
            qa[mf] = *(const bf16x8*)(qcell +
                ((((mtp * 2 + mf) * 8 + wv) << 9) + lane * 8));

        // QK^T
        f32x4 sc[2][8];
        #pragma unroll
        for (int nf = 0; nf < 8; ++nf) {
            f32x4 z = { 0.f, 0.f, 0.f, 0.f };
            sc[0][nf] = __builtin_amdgcn_mfma_f32_16x16x32_bf16(qa[0], kb[nf], z, 0, 0, 0);
            sc[1][nf] = __builtin_amdgcn_mfma_f32_16x16x32_bf16(qa[1], kb[nf], z, 0, 0, 0);
        }

        // mask + softmax (16-lane groups own a row)
        float linv[2][4];
        #pragma unroll
        for (int mf = 0; mf < 2; ++mf)
            #pragma unroll
            for (int r = 0; r < 4; ++r) {
                int row = mtp * 32 + mf * 16 + rg * 4 + r;
                unsigned mb = maskb[row * 16 + lr];
                float v[8];
                float vmax = -3.4e38f;
                #pragma unroll
                for (int nf = 0; nf < 8; ++nf) {
                    float t = sc[mf][nf][r] * SCALEF;
                    if ((mb >> nf) & 1) t = NEGV;
                    v[nf] = t;
                    vmax = fmaxf(vmax, t);
                }
                #pragma unroll
                for (int d = 1; d < 16; d <<= 1)
                    vmax = fmaxf(vmax, __shfl_xor(vmax, d, 64));
                float ls = 0.f;
                #pragma unroll
                for (int nf = 0; nf < 8; ++nf) {
                    float p = __expf(v[nf] - vmax);
                    ls += p;
                    sc[mf][nf][r] = p;
                }
                #pragma unroll
                for (int d = 1; d < 16; d <<= 1)
                    ls += __shfl_xor(ls, d, 64);
                linv[mf][r] = 1.f / ls;
            }

        // P -> wave-private LDS (no barrier needed: same-wave ds order)
        #pragma unroll
        for (int mf = 0; mf < 2; ++mf)
            #pragma unroll
            for (int r = 0; r < 4; ++r) {
                int q = mf * 16 + rg * 4 + r;
                #pragma unroll
                for (int nf = 0; nf < 8; ++nf)
                    Pw[q * 136 + nf * 16 + lr] = (short)f2bf(sc[mf][nf][r]);
            }

        // PV: A = P (LDS), B = V^T frags (global/L2, coalesced)
        f32x4 xacc[2][2];
        {
            f32x4 z = { 0.f, 0.f, 0.f, 0.f };
            xacc[0][0] = z; xacc[0][1] = z; xacc[1][0] = z; xacc[1][1] = z;
        }
        #pragma unroll
        for (int kk = 0; kk < 4; ++kk) {
            bf16x8 pa0 = *(const bf16x8*)&Pw[lr * 136 + kk * 32 + k8];
            bf16x8 pa1 = *(const bf16x8*)&Pw[(16 + lr) * 136 + kk * 32 + k8];
            bf16x8 vb0 = *(const bf16x8*)(vcell + ((((wv * 2 + 0) * 4 + kk) << 9) + lane * 8));
            bf16x8 vb1 = *(const bf16x8*)(vcell + ((((wv * 2 + 1) * 4 + kk) << 9) + lane * 8));
            xacc[0][0] = __builtin_amdgcn_mfma_f32_16x16x32_bf16(pa0, vb0, xacc[0][0], 0, 0, 0);
            xacc[0][1] = __builtin_amdgcn_mfma_f32_16x16x32_bf16(pa0, vb1, xacc[0][1], 0, 0, 0);
            xacc[1][0] = __builtin_amdgcn_mfma_f32_16x16x32_bf16(pa1, vb0, xacc[1][0], 0, 0, 0);
            xacc[1][1] = __builtin_amdgcn_mfma_f32_16x16x32_bf16(pa1, vb1, xacc[1][1], 0, 0, 0);
        }

        // normalized bf16 x -> shared xs tile (cols = this head's 32 ch)
        #pragma unroll
        for (int mf = 0; mf < 2; ++mf)
            #pragma unroll
            for (int nf = 0; nf < 2; ++nf)
                #pragma unroll
                for (int r = 0; r < 4; ++r) {
                    int t = mtp * 32 + mf * 16 + rg * 4 + r;
                    xs[t * XP + wv * HD + nf * 16 + lr] =
                        (short)f2bf(xacc[mf][nf][r] * linv[mf][r]);
                }
    }

    __syncthreads();   // xs complete; all q/k cell reads done

    // ---- out-projection: wave owns rows wv*16..wv*16+15 ----
    f32x4 acc[16];
    {
        f32x4 z = { 0.f, 0.f, 0.f, 0.f };
        #pragma unroll
        for (int nf = 0; nf < 16; ++nf) acc[nf] = z;
    }
    #pragma unroll
    for (int dc = 0; dc < 8; ++dc) {
        bf16x8 aa = *(const bf16x8*)&xs[(wv * 16 + lr) * XP + dc * 32 + k8];
        #pragma unroll
        for (int nf = 0; nf < 16; ++nf) {
            bf16x8 bb = *(const bf16x8*)(owf + (((nf * 8 + dc) << 9) + lane * 8));
            acc[nf] = __builtin_amdgcn_mfma_f32_16x16x32_bf16(aa, bb, acc[nf], 0, 0, 0);
        }
    }

    float* fcell = (float*)qkb + (size_t)bn * 32768;
    #pragma unroll
    for (int nf = 0; nf < 16; ++nf) {
        float bb = ob[nf * 16 + lr];
        #pragma unroll
        for (int r = 0; r < 4; ++r)
            fcell[(wv * 16 + rg * 4 + r) * DD + nf * 16 + lr] = acc[nf][r] + bb;
    }
}

extern "C" void kernel_launch(void* const* d_in, const int* in_sizes, int n_in,
                              void* d_out, int out_size, void* d_ws, size_t ws_size,
                              hipStream_t stream) {
    (void)in_sizes; (void)n_in; (void)out_size; (void)ws_size;
    const float* query = (const float*)d_in[0];
    const float* key   = (const float*)d_in[1];
    const float* value = (const float*)d_in[2];
    const void*  kpm   = d_in[3];
    const int*   amask = (const int*)d_in[4];
    const float* wq = (const float*)d_in[5];
    const float* bq = (const float*)d_in[6];
    const float* wk = (const float*)d_in[7];
    const float* bk = (const float*)d_in[8];
    const float* vw = (const float*)d_in[9];
    const float* vb = (const float*)d_in[10];
    const float* ow = (const float*)d_in[11];
    const float* ob = (const float*)d_in[12];

    short* qkb = (short*)d_out;
    unsigned short* wqf = (unsigned short*)d_ws;        // 196608
    unsigned short* wkf = wqf + 196608;                 // 196608
    unsigned short* vwf = wkf + 196608;                 // 65536
    unsigned short* owf = vwf + 65536;                  // 65536  (end 524288)
    int* flagp = (int*)((short*)d_ws + 524288);
    short* vbuf = (short*)d_ws + 524296;                // 16.77M shorts (32 MiB)

    cvt_weights_kernel<<<dim3(1281), dim3(256), 0, stream>>>(
        wq, wk, vw, ow, (const unsigned char*)kpm, wqf, wkf, vwf, owf, flagp);

    proj_kernel<<<dim3(512, 3), dim3(512), 0, stream>>>(
        query, key, value, wqf, wkf, vwf, bq, bk, vb, qkb, vbuf);

    attn_out_fused<<<dim3(512), dim3(512), 0, stream>>>(
        qkb, vbuf, owf, ob, (const unsigned char*)kpm, (const int*)kpm,
        amask, flagp);
}